// Round 11
// baseline (116.262 us; speedup 1.0000x reference)
//
#include <hip/hip_runtime.h>
#include <stdint.h>

// Fused 3-level B3-spline UWT, fp32 in/out. x:(16,1024,1024)->out:(16,4,1024,1024).
// 64x64 tile, 2 barriers, 36.1 KB LDS -> 4 blocks/CU (16 waves).
//  stage:  global f32 -> xs bf16 (92 rows x 48 dwords, uint2-slot XOR swizzle)
//  passA:  per (row,16-col group): unpack 48 floats, horizontal a-trous cascade
//          h1->h2->h3 in registers; u1,u2 -> bf16 tiles; u3 -> bf16 IN-PLACE
//          over xs (wave w owns rows [16w,16w+16) for both reads and writes)
//  passB:  vertical 5/13/29-tap dense convs (b64 reads, uniform 4 dw/bank);
//          w1 = x(global re-read, L2-hot) - c1
// All XOR swizzles act within 8-aligned slot blocks => always in-range, and
// preimage counting gives uniform bank load for every access shape used.

typedef float f4v __attribute__((ext_vector_type(4)));

constexpr int TB  = 256;
constexpr int VH  = 14;       // vertical halo (2+4+8)
constexpr int XR  = 92;       // xs rows
constexpr int XSP = 48;       // xs row pitch in dwords (96 bf16 = 24 uint2 slots)
constexpr int U1P = 32;       // u1 row pitch in dwords (64 bf16 = 16 uint2 slots)
constexpr int U1R = 68;       // u1 rows: frame [12,80)
constexpr int U2P = 32;
constexpr int U2R = 76;       // u2 rows: frame [8,84)
constexpr int HW  = 1024 * 1024;

__device__ constexpr float K13[13] = {
    1.f/256, 4.f/256, 10.f/256, 20.f/256, 31.f/256, 40.f/256, 44.f/256,
    40.f/256, 31.f/256, 20.f/256, 10.f/256, 4.f/256, 1.f/256};
__device__ constexpr float K29[29] = {
    1.f/4096,   4.f/4096,  10.f/4096,  20.f/4096,  35.f/4096,  56.f/4096,
    84.f/4096, 120.f/4096, 161.f/4096, 204.f/4096, 246.f/4096, 284.f/4096,
    315.f/4096, 336.f/4096, 344.f/4096, 336.f/4096, 315.f/4096, 284.f/4096,
    246.f/4096, 204.f/4096, 161.f/4096, 120.f/4096,  84.f/4096,  56.f/4096,
    35.f/4096,  20.f/4096,  10.f/4096,   4.f/4096,   1.f/4096};

__device__ __forceinline__ int refl(int i) {
    return i < 0 ? -i : (i >= 1024 ? 2046 - i : i);
}
// bf16 pack (round-half-up) / unpack (lo = element 0)
__device__ __forceinline__ uint32_t pk(float a, float b) {
    return ((__builtin_bit_cast(uint32_t, a) + 0x8000u) >> 16)
         | ((__builtin_bit_cast(uint32_t, b) + 0x8000u) & 0xFFFF0000u);
}
__device__ __forceinline__ float ulo(uint32_t w) { return __builtin_bit_cast(float, w << 16); }
__device__ __forceinline__ float uhi(uint32_t w) { return __builtin_bit_cast(float, w & 0xFFFF0000u); }

__global__ __launch_bounds__(TB, 4)
void uwt3_kernel(const float* __restrict__ x, float* __restrict__ out)
{
    __shared__ __align__(16) uint32_t ldsw[XR * XSP + U1R * U1P + U2R * U2P]; // 9024 dw = 36.1 KB
    uint32_t* xsw = ldsw;                       // stage (bf16 x) + in-place u3
    uint32_t* u1b = ldsw + XR * XSP;
    uint32_t* u2b = u1b + U1R * U1P;

    const int tid = threadIdx.x;

    // bijective XCD chunk swizzle (4096 % 8 == 0)
    const int flat = blockIdx.x;
    const int swz  = (flat & 7) * 512 + (flat >> 3);
    const int bxi = swz & 15;
    const int byi = (swz >> 4) & 15;
    const int bz  = swz >> 8;
    const int bx = bxi * 64;
    const int by = byi * 64;

    const float* xp = x + (size_t)bz * HW;
    float* op = out + (size_t)bz * 4 * HW;

    // ---- stage: x rows [by-14,by+78), cols [bx-16,bx+80) -> bf16 xs ----
    for (int e = tid; e < XR * 24; e += TB) {
        const int r = e / 24, m = e - r * 24;
        const int gr = refl(by - VH + r);
        const int gc0 = bx - 16 + 4 * m;
        f4v v;
        if (gc0 >= 0 && gc0 <= 1020) {
            v = *(const f4v*)(xp + (size_t)gr * 1024 + gc0);
        } else {
#pragma unroll
            for (int q = 0; q < 4; ++q) v[q] = xp[(size_t)gr * 1024 + refl(gc0 + q)];
        }
        uint2 w;
        w.x = pk(v[0], v[1]);
        w.y = pk(v[2], v[3]);
        *(uint2*)(xsw + r * XSP + 2 * (m ^ (r & 7))) = w;
    }
    __syncthreads();

    // ---- passA: horizontal cascade; u1/u2 bf16 tiles; u3 bf16 in-place ----
    for (int t = tid; t < XR * 4; t += TB) {
        const int gi = t & 3;
        const int rp = t >> 2;
        const int key = rp & 7;
        const uint32_t* base = xsw + rp * XSP;
        float F[48];
#pragma unroll
        for (int j = 0; j < 12; ++j) {
            const uint2 w = *(const uint2*)(base + 2 * ((4 * gi + j) ^ key));
            F[4*j]     = ulo(w.x);
            F[4*j + 1] = uhi(w.x);
            F[4*j + 2] = ulo(w.y);
            F[4*j + 3] = uhi(w.y);
        }
        // h1 (d=1): F[i] <- h1 @ frame col i+2
#pragma unroll
        for (int i = 2; i < 42; ++i)
            F[i] = 0.0625f * (F[i] + F[i + 4]) + 0.25f * (F[i + 1] + F[i + 3])
                 + 0.375f * F[i + 2];
        if (rp >= 12 && rp < 80) {      // u1 = h1 center = F[14..30)
            const int ur = rp - 12, k15 = ur & 15;
            uint32_t* d = u1b + ur * U1P;
#pragma unroll
            for (int j = 0; j < 4; ++j) {
                uint2 w;
                w.x = pk(F[14 + 4*j], F[15 + 4*j]);
                w.y = pk(F[16 + 4*j], F[17 + 4*j]);
                *(uint2*)(d + 2 * ((4 * gi + j) ^ k15)) = w;
            }
        }
        // h2 (d=2): F[i] <- h2 @ frame col i+6
#pragma unroll
        for (int i = 2; i < 34; ++i)
            F[i] = 0.0625f * (F[i] + F[i + 8]) + 0.25f * (F[i + 2] + F[i + 6])
                 + 0.375f * F[i + 4];
        if (rp >= 8 && rp < 84) {       // u2 = h2 center = F[10..26)
            const int ur = rp - 8, k15 = ur & 15;
            uint32_t* d = u2b + ur * U2P;
#pragma unroll
            for (int j = 0; j < 4; ++j) {
                uint2 w;
                w.x = pk(F[10 + 4*j], F[11 + 4*j]);
                w.y = pk(F[12 + 4*j], F[13 + 4*j]);
                *(uint2*)(d + 2 * ((4 * gi + j) ^ k15)) = w;
            }
        }
        // h3 (d=4): F[i] <- h3 @ frame col i+14
#pragma unroll
        for (int i = 2; i < 18; ++i)
            F[i] = 0.0625f * (F[i] + F[i + 16]) + 0.25f * (F[i + 4] + F[i + 12])
                 + 0.375f * F[i + 8];
        // u3 = h3 center = F[2..18) -> bf16, in-place into xs row rp
        {
            uint32_t* d = xsw + rp * XSP;
#pragma unroll
            for (int j = 0; j < 4; ++j) {
                uint2 w;
                w.x = pk(F[2 + 4*j], F[3 + 4*j]);
                w.y = pk(F[4 + 4*j], F[5 + 4*j]);
                *(uint2*)(d + 2 * ((4 * gi + j) ^ key)) = w;
            }
        }
    }
    __syncthreads();

    // ---- passB: vertical convs + all 4 outputs; thread = (f4-col, 4-row strip) ----
    const int fc = tid & 15;
    const int r0 = (tid >> 4) * 4;
    const size_t gbase = (size_t)(by + r0) * 1024 + bx + 4 * fc;

    // c1 = V1 u1 (5-tap)
    f4v c1[4];
    {
        f4v u1r[8];
#pragma unroll
        for (int i = 0; i < 8; ++i) {
            const int rr = r0 + i;
            const uint2 w = *(const uint2*)(u1b + rr * U1P + 2 * (fc ^ (rr & 15)));
            u1r[i] = f4v{ulo(w.x), uhi(w.x), ulo(w.y), uhi(w.y)};
        }
#pragma unroll
        for (int j = 0; j < 4; ++j)
            c1[j] = 0.0625f * (u1r[j] + u1r[j + 4]) + 0.25f * (u1r[j + 1] + u1r[j + 3])
                  + 0.375f * u1r[j + 2];
    }
    // w1 = x - c1 (x re-read from global, L2/L3-hot)
#pragma unroll
    for (int j = 0; j < 4; ++j) {
        const f4v xc = *(const f4v*)(xp + gbase + (size_t)j * 1024);
        __builtin_nontemporal_store(xc - c1[j], (f4v*)(op + 0 * HW + gbase + (size_t)j * 1024));
    }

    // c2 = V2 u2 (13-tap dense)
    f4v c2[4] = {{0,0,0,0},{0,0,0,0},{0,0,0,0},{0,0,0,0}};
#pragma unroll
    for (int i = 0; i < 16; ++i) {
        const int rr = r0 + i;
        const uint2 w = *(const uint2*)(u2b + rr * U2P + 2 * (fc ^ (rr & 15)));
        const f4v v = f4v{ulo(w.x), uhi(w.x), ulo(w.y), uhi(w.y)};
#pragma unroll
        for (int j = 0; j < 4; ++j) {
            const int m = i - j;
            if (m >= 0 && m <= 12) c2[j] += K13[m] * v;
        }
    }
#pragma unroll
    for (int j = 0; j < 4; ++j)
        __builtin_nontemporal_store(c1[j] - c2[j], (f4v*)(op + 1 * HW + gbase + (size_t)j * 1024));

    // c3 = V3 u3 (29-tap dense, u3 bf16 in xs arena)
    f4v c3[4] = {{0,0,0,0},{0,0,0,0},{0,0,0,0},{0,0,0,0}};
#pragma unroll
    for (int i = 0; i < 32; ++i) {
        const int rr = r0 + i;
        const uint2 w = *(const uint2*)(xsw + rr * XSP + 2 * (fc ^ (rr & 7)));
        const f4v v = f4v{ulo(w.x), uhi(w.x), ulo(w.y), uhi(w.y)};
#pragma unroll
        for (int j = 0; j < 4; ++j) {
            const int m = i - j;
            if (m >= 0 && m <= 28) c3[j] += K29[m] * v;
        }
    }
#pragma unroll
    for (int j = 0; j < 4; ++j) {
        __builtin_nontemporal_store(c2[j] - c3[j], (f4v*)(op + 2 * HW + gbase + (size_t)j * 1024));
        __builtin_nontemporal_store(c3[j],        (f4v*)(op + 3 * HW + gbase + (size_t)j * 1024));
    }
}

extern "C" void kernel_launch(void* const* d_in, const int* in_sizes, int n_in,
                              void* d_out, int out_size, void* d_ws, size_t ws_size,
                              hipStream_t stream)
{
    const float* x = (const float*)d_in[0];
    float* out = (float*)d_out;
    uwt3_kernel<<<dim3(4096), dim3(TB), 0, stream>>>(x, out);
}

// Round 12
// 82.191 us; speedup vs baseline: 1.4145x; 1.4145x over previous
//
#include <hip/hip_runtime.h>
#include <stdint.h>

// Fused 3-level B3-spline UWT, fp32 in/out. x:(16,1024,1024)->out:(16,4,1024,1024).
// 64x64 tile, 2 barriers, 36.1 KB LDS -> 4 blocks/CU by LDS; NO min-waves
// launch-bounds clamp (R9/R11 showed it forces VGPR=64-68 + scratch spill:
// FETCH +79 MB, WRITE +176 MB, dur +36 us). Natural VGPR demand ~60-100.
//  stage:  global f32 -> xs bf16 (92 rows x 48 dwords, uint2-slot XOR swizzle)
//  passA:  per (row,16-col group): unpack 48 floats, horizontal a-trous cascade
//          h1->h2->h3 in registers; u1,u2 -> bf16 tiles; u3 -> bf16 IN-PLACE
//          over xs (each item writes only its own row => race-free)
//  passB:  vertical 5/13/29-tap dense convs (b64 reads, uniform 4 dw/bank);
//          w1 = x(global re-read, L2/L3-hot) - c1

typedef float f4v __attribute__((ext_vector_type(4)));

constexpr int TB  = 256;
constexpr int VH  = 14;       // vertical halo (2+4+8)
constexpr int XR  = 92;       // xs rows
constexpr int XSP = 48;       // xs row pitch in dwords (96 bf16 = 24 uint2 slots)
constexpr int U1P = 32;       // u1 row pitch in dwords (64 bf16 = 16 uint2 slots)
constexpr int U1R = 68;       // u1 rows: frame [12,80)
constexpr int U2P = 32;
constexpr int U2R = 76;       // u2 rows: frame [8,84)
constexpr int HW  = 1024 * 1024;

__device__ constexpr float K13[13] = {
    1.f/256, 4.f/256, 10.f/256, 20.f/256, 31.f/256, 40.f/256, 44.f/256,
    40.f/256, 31.f/256, 20.f/256, 10.f/256, 4.f/256, 1.f/256};
__device__ constexpr float K29[29] = {
    1.f/4096,   4.f/4096,  10.f/4096,  20.f/4096,  35.f/4096,  56.f/4096,
    84.f/4096, 120.f/4096, 161.f/4096, 204.f/4096, 246.f/4096, 284.f/4096,
    315.f/4096, 336.f/4096, 344.f/4096, 336.f/4096, 315.f/4096, 284.f/4096,
    246.f/4096, 204.f/4096, 161.f/4096, 120.f/4096,  84.f/4096,  56.f/4096,
    35.f/4096,  20.f/4096,  10.f/4096,   4.f/4096,   1.f/4096};

__device__ __forceinline__ int refl(int i) {
    return i < 0 ? -i : (i >= 1024 ? 2046 - i : i);
}
// bf16 pack (round-half-up) / unpack (lo = element 0)
__device__ __forceinline__ uint32_t pk(float a, float b) {
    return ((__builtin_bit_cast(uint32_t, a) + 0x8000u) >> 16)
         | ((__builtin_bit_cast(uint32_t, b) + 0x8000u) & 0xFFFF0000u);
}
__device__ __forceinline__ float ulo(uint32_t w) { return __builtin_bit_cast(float, w << 16); }
__device__ __forceinline__ float uhi(uint32_t w) { return __builtin_bit_cast(float, w & 0xFFFF0000u); }

__global__ __launch_bounds__(TB)
void uwt3_kernel(const float* __restrict__ x, float* __restrict__ out)
{
    __shared__ __align__(16) uint32_t ldsw[XR * XSP + U1R * U1P + U2R * U2P]; // 9024 dw = 36.1 KB
    uint32_t* xsw = ldsw;                       // stage (bf16 x) + in-place u3
    uint32_t* u1b = ldsw + XR * XSP;
    uint32_t* u2b = u1b + U1R * U1P;

    const int tid = threadIdx.x;

    // bijective XCD chunk swizzle (4096 % 8 == 0)
    const int flat = blockIdx.x;
    const int swz  = (flat & 7) * 512 + (flat >> 3);
    const int bxi = swz & 15;
    const int byi = (swz >> 4) & 15;
    const int bz  = swz >> 8;
    const int bx = bxi * 64;
    const int by = byi * 64;

    const float* xp = x + (size_t)bz * HW;
    float* op = out + (size_t)bz * 4 * HW;

    // ---- stage: x rows [by-14,by+78), cols [bx-16,bx+80) -> bf16 xs ----
    for (int e = tid; e < XR * 24; e += TB) {
        const int r = e / 24, m = e - r * 24;
        const int gr = refl(by - VH + r);
        const int gc0 = bx - 16 + 4 * m;
        f4v v;
        if (gc0 >= 0 && gc0 <= 1020) {
            v = *(const f4v*)(xp + (size_t)gr * 1024 + gc0);
        } else {
#pragma unroll
            for (int q = 0; q < 4; ++q) v[q] = xp[(size_t)gr * 1024 + refl(gc0 + q)];
        }
        uint2 w;
        w.x = pk(v[0], v[1]);
        w.y = pk(v[2], v[3]);
        *(uint2*)(xsw + r * XSP + 2 * (m ^ (r & 7))) = w;
    }
    __syncthreads();

    // ---- passA: horizontal cascade; u1/u2 bf16 tiles; u3 bf16 in-place ----
    for (int t = tid; t < XR * 4; t += TB) {
        const int gi = t & 3;
        const int rp = t >> 2;
        const int key = rp & 7;
        const uint32_t* base = xsw + rp * XSP;
        float F[48];
#pragma unroll
        for (int j = 0; j < 12; ++j) {
            const uint2 w = *(const uint2*)(base + 2 * ((4 * gi + j) ^ key));
            F[4*j]     = ulo(w.x);
            F[4*j + 1] = uhi(w.x);
            F[4*j + 2] = ulo(w.y);
            F[4*j + 3] = uhi(w.y);
        }
        // h1 (d=1): F[i] <- h1 @ frame col i+2
#pragma unroll
        for (int i = 2; i < 42; ++i)
            F[i] = 0.0625f * (F[i] + F[i + 4]) + 0.25f * (F[i + 1] + F[i + 3])
                 + 0.375f * F[i + 2];
        if (rp >= 12 && rp < 80) {      // u1 = h1 center = F[14..30)
            const int ur = rp - 12, k15 = ur & 15;
            uint32_t* d = u1b + ur * U1P;
#pragma unroll
            for (int j = 0; j < 4; ++j) {
                uint2 w;
                w.x = pk(F[14 + 4*j], F[15 + 4*j]);
                w.y = pk(F[16 + 4*j], F[17 + 4*j]);
                *(uint2*)(d + 2 * ((4 * gi + j) ^ k15)) = w;
            }
        }
        // h2 (d=2): F[i] <- h2 @ frame col i+6
#pragma unroll
        for (int i = 2; i < 34; ++i)
            F[i] = 0.0625f * (F[i] + F[i + 8]) + 0.25f * (F[i + 2] + F[i + 6])
                 + 0.375f * F[i + 4];
        if (rp >= 8 && rp < 84) {       // u2 = h2 center = F[10..26)
            const int ur = rp - 8, k15 = ur & 15;
            uint32_t* d = u2b + ur * U2P;
#pragma unroll
            for (int j = 0; j < 4; ++j) {
                uint2 w;
                w.x = pk(F[10 + 4*j], F[11 + 4*j]);
                w.y = pk(F[12 + 4*j], F[13 + 4*j]);
                *(uint2*)(d + 2 * ((4 * gi + j) ^ k15)) = w;
            }
        }
        // h3 (d=4): F[i] <- h3 @ frame col i+14
#pragma unroll
        for (int i = 2; i < 18; ++i)
            F[i] = 0.0625f * (F[i] + F[i + 16]) + 0.25f * (F[i + 4] + F[i + 12])
                 + 0.375f * F[i + 8];
        // u3 = h3 center = F[2..18) -> bf16, in-place into xs row rp
        {
            uint32_t* d = xsw + rp * XSP;
#pragma unroll
            for (int j = 0; j < 4; ++j) {
                uint2 w;
                w.x = pk(F[2 + 4*j], F[3 + 4*j]);
                w.y = pk(F[4 + 4*j], F[5 + 4*j]);
                *(uint2*)(d + 2 * ((4 * gi + j) ^ key)) = w;
            }
        }
    }
    __syncthreads();

    // ---- passB: vertical convs + all 4 outputs; thread = (f4-col, 4-row strip) ----
    const int fc = tid & 15;
    const int r0 = (tid >> 4) * 4;
    const size_t gbase = (size_t)(by + r0) * 1024 + bx + 4 * fc;

    // c1 = V1 u1 (5-tap)
    f4v c1[4];
    {
        f4v u1r[8];
#pragma unroll
        for (int i = 0; i < 8; ++i) {
            const int rr = r0 + i;
            const uint2 w = *(const uint2*)(u1b + rr * U1P + 2 * (fc ^ (rr & 15)));
            u1r[i] = f4v{ulo(w.x), uhi(w.x), ulo(w.y), uhi(w.y)};
        }
#pragma unroll
        for (int j = 0; j < 4; ++j)
            c1[j] = 0.0625f * (u1r[j] + u1r[j + 4]) + 0.25f * (u1r[j + 1] + u1r[j + 3])
                  + 0.375f * u1r[j + 2];
    }
    // w1 = x - c1 (x re-read from global, L2/L3-hot)
#pragma unroll
    for (int j = 0; j < 4; ++j) {
        const f4v xc = *(const f4v*)(xp + gbase + (size_t)j * 1024);
        __builtin_nontemporal_store(xc - c1[j], (f4v*)(op + 0 * HW + gbase + (size_t)j * 1024));
    }

    // c2 = V2 u2 (13-tap dense)
    f4v c2[4] = {{0,0,0,0},{0,0,0,0},{0,0,0,0},{0,0,0,0}};
#pragma unroll
    for (int i = 0; i < 16; ++i) {
        const int rr = r0 + i;
        const uint2 w = *(const uint2*)(u2b + rr * U2P + 2 * (fc ^ (rr & 15)));
        const f4v v = f4v{ulo(w.x), uhi(w.x), ulo(w.y), uhi(w.y)};
#pragma unroll
        for (int j = 0; j < 4; ++j) {
            const int m = i - j;
            if (m >= 0 && m <= 12) c2[j] += K13[m] * v;
        }
    }
#pragma unroll
    for (int j = 0; j < 4; ++j)
        __builtin_nontemporal_store(c1[j] - c2[j], (f4v*)(op + 1 * HW + gbase + (size_t)j * 1024));

    // c3 = V3 u3 (29-tap dense, u3 bf16 in xs arena)
    f4v c3[4] = {{0,0,0,0},{0,0,0,0},{0,0,0,0},{0,0,0,0}};
#pragma unroll
    for (int i = 0; i < 32; ++i) {
        const int rr = r0 + i;
        const uint2 w = *(const uint2*)(xsw + rr * XSP + 2 * (fc ^ (rr & 7)));
        const f4v v = f4v{ulo(w.x), uhi(w.x), ulo(w.y), uhi(w.y)};
#pragma unroll
        for (int j = 0; j < 4; ++j) {
            const int m = i - j;
            if (m >= 0 && m <= 28) c3[j] += K29[m] * v;
        }
    }
#pragma unroll
    for (int j = 0; j < 4; ++j) {
        __builtin_nontemporal_store(c2[j] - c3[j], (f4v*)(op + 2 * HW + gbase + (size_t)j * 1024));
        __builtin_nontemporal_store(c3[j],        (f4v*)(op + 3 * HW + gbase + (size_t)j * 1024));
    }
}

extern "C" void kernel_launch(void* const* d_in, const int* in_sizes, int n_in,
                              void* d_out, int out_size, void* d_ws, size_t ws_size,
                              hipStream_t stream)
{
    const float* x = (const float*)d_in[0];
    float* out = (float*)d_out;
    uwt3_kernel<<<dim3(4096), dim3(TB), 0, stream>>>(x, out);
}

// Round 13
// 75.429 us; speedup vs baseline: 1.5413x; 1.0896x over previous
//
#include <hip/hip_runtime.h>
#include <stdint.h>

// Fused 3-level B3-spline UWT, fp32 in/out. x:(16,1024,1024)->out:(16,4,1024,1024).
// 64x64 tile, 2 barriers, 36.5 KB LDS -> 4 blocks/CU.
// COLUMN-MAJOR bf16 LDS tiles with odd pitches (93/69/77 uint2-slots): every
// access shape is provably uniform across bank pairs WITHOUT any XOR swizzle,
// and all LDS addresses are base + immediate offset (affine) -> minimal VALU.
//  stage:  global f32 -> xs bf16 col-major [24 cols][93 rows]
//  passA:  per (row,16-col group): unpack 48 floats, horizontal a-trous cascade
//          h1->h2->h3; u1,u2 -> bf16 col-major tiles; u3 -> IN-PLACE into xs
//          cols 0..15 (all 4 items of a row share one wave => lockstep-safe)
//  passB:  vertical 5/13/29-tap dense convs streaming down columns
//          (b64 reads, immediate offsets); w1 = x(global re-read, L3-hot) - c1

typedef float f4v __attribute__((ext_vector_type(4)));

constexpr int TB  = 256;
constexpr int VH  = 14;     // vertical halo (2+4+8)
constexpr int XR  = 92;     // xs rows
constexpr int XCP = 93;     // xs column pitch (uint2 slots), odd
constexpr int XC  = 24;     // xs uint2-columns (96 bf16)
constexpr int U1P = 69;     // u1 column pitch (68 rows used), 69%16=5
constexpr int U2P = 77;     // u2 column pitch (76 rows used), 77%16=13
constexpr int HW  = 1024 * 1024;

__device__ constexpr float K13[13] = {
    1.f/256, 4.f/256, 10.f/256, 20.f/256, 31.f/256, 40.f/256, 44.f/256,
    40.f/256, 31.f/256, 20.f/256, 10.f/256, 4.f/256, 1.f/256};
__device__ constexpr float K29[29] = {
    1.f/4096,   4.f/4096,  10.f/4096,  20.f/4096,  35.f/4096,  56.f/4096,
    84.f/4096, 120.f/4096, 161.f/4096, 204.f/4096, 246.f/4096, 284.f/4096,
    315.f/4096, 336.f/4096, 344.f/4096, 336.f/4096, 315.f/4096, 284.f/4096,
    246.f/4096, 204.f/4096, 161.f/4096, 120.f/4096,  84.f/4096,  56.f/4096,
    35.f/4096,  20.f/4096,  10.f/4096,   4.f/4096,   1.f/4096};

__device__ __forceinline__ int refl(int i) {
    return i < 0 ? -i : (i >= 1024 ? 2046 - i : i);
}
// bf16 pack (round-half-up) / unpack (lo = element 0)
__device__ __forceinline__ uint32_t pk(float a, float b) {
    return ((__builtin_bit_cast(uint32_t, a) + 0x8000u) >> 16)
         | ((__builtin_bit_cast(uint32_t, b) + 0x8000u) & 0xFFFF0000u);
}
__device__ __forceinline__ float ulo(uint32_t w) { return __builtin_bit_cast(float, w << 16); }
__device__ __forceinline__ float uhi(uint32_t w) { return __builtin_bit_cast(float, w & 0xFFFF0000u); }
__device__ __forceinline__ f4v up4(uint2 w) {
    return f4v{ulo(w.x), uhi(w.x), ulo(w.y), uhi(w.y)};
}

__global__ __launch_bounds__(TB)
void uwt3_kernel(const float* __restrict__ x, float* __restrict__ out)
{
    __shared__ uint2 xsw[XC * XCP];    // 17856 B (stage; cols 0..15 become u3)
    __shared__ uint2 u1b[16 * U1P];    //  8832 B
    __shared__ uint2 u2b[16 * U2P];    //  9856 B   total 36544 B

    const int tid = threadIdx.x;

    // bijective XCD chunk swizzle (4096 % 8 == 0)
    const int flat = blockIdx.x;
    const int swz  = (flat & 7) * 512 + (flat >> 3);
    const int bxi = swz & 15;
    const int byi = (swz >> 4) & 15;
    const int bz  = swz >> 8;
    const int bx = bxi * 64;
    const int by = byi * 64;

    const float* xp = x + (size_t)bz * HW;
    float* op = out + (size_t)bz * 4 * HW;

    // ---- stage: x rows [by-14,by+78), cols [bx-16,bx+80) -> bf16 col-major ----
    for (int e = tid; e < XR * 24; e += TB) {
        const int r = e / 24, m = e - r * 24;
        const int gr = refl(by - VH + r);
        const int gc0 = bx - 16 + 4 * m;
        f4v v;
        if (gc0 >= 0 && gc0 <= 1020) {
            v = *(const f4v*)(xp + (size_t)gr * 1024 + gc0);
        } else {
#pragma unroll
            for (int q = 0; q < 4; ++q) v[q] = xp[(size_t)gr * 1024 + refl(gc0 + q)];
        }
        xsw[m * XCP + r] = uint2{pk(v[0], v[1]), pk(v[2], v[3])};
    }
    __syncthreads();

    // ---- passA: horizontal cascade; u1/u2 col-major; u3 in-place over xs ----
    for (int t = tid; t < XR * 4; t += TB) {
        const int gi = t & 3;
        const int rp = t >> 2;
        const uint2* base = xsw + (4 * gi) * XCP + rp;
        float F[48];
#pragma unroll
        for (int j = 0; j < 12; ++j) {
            const uint2 w = base[j * XCP];
            F[4*j]     = ulo(w.x);
            F[4*j + 1] = uhi(w.x);
            F[4*j + 2] = ulo(w.y);
            F[4*j + 3] = uhi(w.y);
        }
        // h1 (d=1): F[i] <- h1 @ frame col 16gi + i + 2
#pragma unroll
        for (int i = 2; i < 42; ++i)
            F[i] = 0.0625f * (F[i] + F[i + 4]) + 0.25f * (F[i + 1] + F[i + 3])
                 + 0.375f * F[i + 2];
        if (rp >= 12 && rp < 80) {      // u1 = h1 center = F[14..30)
            uint2* d = u1b + (4 * gi) * U1P + (rp - 12);
#pragma unroll
            for (int j = 0; j < 4; ++j)
                d[j * U1P] = uint2{pk(F[14 + 4*j], F[15 + 4*j]),
                                   pk(F[16 + 4*j], F[17 + 4*j])};
        }
        // h2 (d=2): F[i] <- h2 @ frame col 16gi + i + 6
#pragma unroll
        for (int i = 2; i < 34; ++i)
            F[i] = 0.0625f * (F[i] + F[i + 8]) + 0.25f * (F[i + 2] + F[i + 6])
                 + 0.375f * F[i + 4];
        if (rp >= 8 && rp < 84) {       // u2 = h2 center = F[10..26)
            uint2* d = u2b + (4 * gi) * U2P + (rp - 8);
#pragma unroll
            for (int j = 0; j < 4; ++j)
                d[j * U2P] = uint2{pk(F[10 + 4*j], F[11 + 4*j]),
                                   pk(F[12 + 4*j], F[13 + 4*j])};
        }
        // h3 (d=4): F[i] <- h3 @ frame col 16gi + i + 14
#pragma unroll
        for (int i = 2; i < 18; ++i)
            F[i] = 0.0625f * (F[i] + F[i + 16]) + 0.25f * (F[i + 4] + F[i + 12])
                 + 0.375f * F[i + 8];
        // u3 = h3 center = F[2..18) -> xs cols [4gi,4gi+4), row rp (in-place)
        {
            uint2* d = xsw + (4 * gi) * XCP + rp;
#pragma unroll
            for (int j = 0; j < 4; ++j)
                d[j * XCP] = uint2{pk(F[2 + 4*j], F[3 + 4*j]),
                                   pk(F[4 + 4*j], F[5 + 4*j])};
        }
    }
    __syncthreads();

    // ---- passB: vertical convs + all 4 outputs; thread = (f4-col, 4-row strip) ----
    const int fc = tid & 15;
    const int r0 = (tid >> 4) * 4;
    const size_t gbase = (size_t)(by + r0) * 1024 + bx + 4 * fc;

    // issue x re-read early (L2/L3-hot) to hide latency under c1
    f4v xc[4];
#pragma unroll
    for (int j = 0; j < 4; ++j)
        xc[j] = *(const f4v*)(xp + gbase + (size_t)j * 1024);

    // c1 = V1 u1 (5-tap), column stream
    f4v c1[4];
    {
        const uint2* b1 = u1b + fc * U1P + r0;
        f4v u1r[8];
#pragma unroll
        for (int i = 0; i < 8; ++i) u1r[i] = up4(b1[i]);
#pragma unroll
        for (int j = 0; j < 4; ++j)
            c1[j] = 0.0625f * (u1r[j] + u1r[j + 4]) + 0.25f * (u1r[j + 1] + u1r[j + 3])
                  + 0.375f * u1r[j + 2];
    }
#pragma unroll
    for (int j = 0; j < 4; ++j)
        __builtin_nontemporal_store(xc[j] - c1[j],
            (f4v*)(op + 0 * HW + gbase + (size_t)j * 1024));

    // c2 = V2 u2 (13-tap dense), column stream
    f4v c2[4] = {{0,0,0,0},{0,0,0,0},{0,0,0,0},{0,0,0,0}};
    {
        const uint2* b2 = u2b + fc * U2P + r0;
#pragma unroll
        for (int i = 0; i < 16; ++i) {
            const f4v v = up4(b2[i]);
#pragma unroll
            for (int j = 0; j < 4; ++j) {
                const int m = i - j;
                if (m >= 0 && m <= 12) c2[j] += K13[m] * v;
            }
        }
    }
#pragma unroll
    for (int j = 0; j < 4; ++j)
        __builtin_nontemporal_store(c1[j] - c2[j],
            (f4v*)(op + 1 * HW + gbase + (size_t)j * 1024));

    // c3 = V3 u3 (29-tap dense), u3 in xs cols 0..15, column stream
    f4v c3[4] = {{0,0,0,0},{0,0,0,0},{0,0,0,0},{0,0,0,0}};
    {
        const uint2* b3 = xsw + fc * XCP + r0;
#pragma unroll
        for (int i = 0; i < 32; ++i) {
            const f4v v = up4(b3[i]);
#pragma unroll
            for (int j = 0; j < 4; ++j) {
                const int m = i - j;
                if (m >= 0 && m <= 28) c3[j] += K29[m] * v;
            }
        }
    }
#pragma unroll
    for (int j = 0; j < 4; ++j) {
        __builtin_nontemporal_store(c2[j] - c3[j],
            (f4v*)(op + 2 * HW + gbase + (size_t)j * 1024));
        __builtin_nontemporal_store(c3[j],
            (f4v*)(op + 3 * HW + gbase + (size_t)j * 1024));
    }
}

extern "C" void kernel_launch(void* const* d_in, const int* in_sizes, int n_in,
                              void* d_out, int out_size, void* d_ws, size_t ws_size,
                              hipStream_t stream)
{
    const float* x = (const float*)d_in[0];
    float* out = (float*)d_out;
    uwt3_kernel<<<dim3(4096), dim3(TB), 0, stream>>>(x, out);
}

// Round 15
// 63.422 us; speedup vs baseline: 1.8332x; 1.1893x over previous
//
#include <hip/hip_runtime.h>
#include <stdint.h>

// Fused 3-level B3-spline UWT, fp32 in/out. x:(16,1024,1024)->out:(16,4,1024,1024).
// 64x64 tile, 2 barriers, 36.5 KB LDS -> 4 blocks/CU. Same col-major odd-pitch
// LDS geometry as R13 (provably uniform banks, affine addressing), but all
// tiles hold PACKED f16 pairs and all conv math is half2 (v_pk_fma_f16):
//  stage:  global f32 -> xs f16 col-major via v_cvt_pkrtz (1 op / 2 floats)
//  passA:  horizontal a-trous cascade h1->h2->h3 in h2v H[24] pair registers
//          (h1 odd taps via v_alignbit; h2/h3 taps pair-aligned); u1,u2 -> f16
//          tiles; u3 -> IN-PLACE into xs cols 0..15 (row-ownership race-free)
//  passB:  vertical 5/13/29-tap dense convs as pk-FMA straight off LDS pairs
//          (no unpack); dual even/odd accumulators halve f16 rounding chains;
//          w_i subtractions + stores in f32; w1 = x(global re-read, L3-hot)-c1

typedef float     f4v __attribute__((ext_vector_type(4)));
typedef _Float16  h2v __attribute__((ext_vector_type(2)));

constexpr int TB  = 256;
constexpr int VH  = 14;     // vertical halo (2+4+8)
constexpr int XR  = 92;     // xs rows
constexpr int XCP = 93;     // xs column pitch (uint2 slots), odd
constexpr int U1P = 69;     // u1 column pitch (68 rows used)
constexpr int U2P = 77;     // u2 column pitch (76 rows used)
constexpr int HW  = 1024 * 1024;

__device__ constexpr float K13f[13] = {
    1.f/256, 4.f/256, 10.f/256, 20.f/256, 31.f/256, 40.f/256, 44.f/256,
    40.f/256, 31.f/256, 20.f/256, 10.f/256, 4.f/256, 1.f/256};
__device__ constexpr float K29f[29] = {
    1.f/4096,   4.f/4096,  10.f/4096,  20.f/4096,  35.f/4096,  56.f/4096,
    84.f/4096, 120.f/4096, 161.f/4096, 204.f/4096, 246.f/4096, 284.f/4096,
    315.f/4096, 336.f/4096, 344.f/4096, 336.f/4096, 315.f/4096, 284.f/4096,
    246.f/4096, 204.f/4096, 161.f/4096, 120.f/4096,  84.f/4096,  56.f/4096,
    35.f/4096,  20.f/4096,  10.f/4096,   4.f/4096,   1.f/4096};

__device__ __forceinline__ int refl(int i) {
    return i < 0 ? -i : (i >= 1024 ? 2046 - i : i);
}
__device__ __forceinline__ uint32_t b32(h2v v) { return __builtin_bit_cast(uint32_t, v); }
__device__ __forceinline__ h2v hb(uint32_t v)  { return __builtin_bit_cast(h2v, v); }
// packed f32->f16 convert (round toward zero); bit_cast handles __fp16 vs _Float16
__device__ __forceinline__ uint32_t pkrtz(float a, float b) {
    return __builtin_bit_cast(uint32_t, __builtin_amdgcn_cvt_pkrtz(a, b));
}
// (lo.hi, hi.lo): pair shifted by one element
__device__ __forceinline__ h2v algn(h2v hi, h2v lo) {
    return hb(__builtin_amdgcn_alignbit(b32(hi), b32(lo), 16));
}
__device__ __forceinline__ h2v hsplat(float f) {
    const _Float16 h = (_Float16)f;
    return h2v{h, h};
}
__device__ __forceinline__ f4v tof4(h2v a, h2v b) {
    return f4v{(float)a[0], (float)a[1], (float)b[0], (float)b[1]};
}

__global__ __launch_bounds__(TB)
void uwt3_kernel(const float* __restrict__ x, float* __restrict__ out)
{
    __shared__ uint2 xsw[24 * XCP];    // 17856 B (stage; cols 0..15 become u3)
    __shared__ uint2 u1b[16 * U1P];    //  8832 B
    __shared__ uint2 u2b[16 * U2P];    //  9856 B   total 36544 B

    const int tid = threadIdx.x;

    // bijective XCD chunk swizzle (4096 % 8 == 0)
    const int flat = blockIdx.x;
    const int swz  = (flat & 7) * 512 + (flat >> 3);
    const int bxi = swz & 15;
    const int byi = (swz >> 4) & 15;
    const int bz  = swz >> 8;
    const int bx = bxi * 64;
    const int by = byi * 64;

    const float* xp = x + (size_t)bz * HW;
    float* op = out + (size_t)bz * 4 * HW;

    // ---- stage: x rows [by-14,by+78), cols [bx-16,bx+80) -> f16 col-major ----
    for (int e = tid; e < XR * 24; e += TB) {
        const int r = e / 24, m = e - r * 24;
        const int gr = refl(by - VH + r);
        const int gc0 = bx - 16 + 4 * m;
        f4v v;
        if (gc0 >= 0 && gc0 <= 1020) {
            v = *(const f4v*)(xp + (size_t)gr * 1024 + gc0);
        } else {
#pragma unroll
            for (int q = 0; q < 4; ++q) v[q] = xp[(size_t)gr * 1024 + refl(gc0 + q)];
        }
        xsw[m * XCP + r] = uint2{pkrtz(v[0], v[1]), pkrtz(v[2], v[3])};
    }
    __syncthreads();

    const h2v W0 = hsplat(0.0625f), W1 = hsplat(0.25f), W2 = hsplat(0.375f);

    // ---- passA: pk-f16 horizontal cascade; u1/u2 col-major; u3 in-place ----
    for (int t = tid; t < XR * 4; t += TB) {
        const int gi = t & 3;
        const int rp = t >> 2;
        const uint2* base = xsw + (4 * gi) * XCP + rp;
        h2v H[24];                       // H[p] = (F[2p], F[2p+1])
#pragma unroll
        for (int j = 0; j < 12; ++j) {
            const uint2 w = base[j * XCP];
            H[2*j]   = hb(w.x);
            H[2*j+1] = hb(w.y);
        }
        // h1 (d=1): F'[i] = conv @ frame col 16gi+i+2, i in [2,42) -> pairs 1..20
        {
            h2v roll = algn(H[2], H[1]);          // (F[3],F[4]) = A1 for p=1
#pragma unroll
            for (int p = 1; p <= 20; ++p) {
                const h2v a1 = roll;                 // (F[2p+1],F[2p+2])
                const h2v a3 = algn(H[p+2], H[p+1]); // (F[2p+3],F[2p+4])
                roll = a3;
                H[p] = W0 * (H[p] + H[p+2]) + W1 * (a1 + a3) + W2 * H[p+1];
            }
        }
        if (rp >= 12 && rp < 80) {        // u1 = h1 center = pairs 7..14
            uint2* d = u1b + (4 * gi) * U1P + (rp - 12);
#pragma unroll
            for (int j = 0; j < 4; ++j)
                d[j * U1P] = uint2{b32(H[7 + 2*j]), b32(H[8 + 2*j])};
        }
        // h2 (d=2): pair-aligned taps, pairs 1..16
#pragma unroll
        for (int p = 1; p <= 16; ++p)
            H[p] = W0 * (H[p] + H[p+4]) + W1 * (H[p+1] + H[p+3]) + W2 * H[p+2];
        if (rp >= 8 && rp < 84) {         // u2 = h2 center = pairs 5..12
            uint2* d = u2b + (4 * gi) * U2P + (rp - 8);
#pragma unroll
            for (int j = 0; j < 4; ++j)
                d[j * U2P] = uint2{b32(H[5 + 2*j]), b32(H[6 + 2*j])};
        }
        // h3 (d=4): pair-aligned taps, pairs 1..8
#pragma unroll
        for (int p = 1; p <= 8; ++p)
            H[p] = W0 * (H[p] + H[p+8]) + W1 * (H[p+2] + H[p+6]) + W2 * H[p+4];
        {                                 // u3 = h3 center = pairs 1..8 -> xs
            uint2* d = xsw + (4 * gi) * XCP + rp;
#pragma unroll
            for (int j = 0; j < 4; ++j)
                d[j * XCP] = uint2{b32(H[1 + 2*j]), b32(H[2 + 2*j])};
        }
    }
    __syncthreads();

    // ---- passB: pk-f16 vertical convs; thread = (f4-col, 4-row strip) ----
    const int fc = tid & 15;
    const int r0 = (tid >> 4) * 4;
    const size_t gbase = (size_t)(by + r0) * 1024 + bx + 4 * fc;

    // issue x re-read early (L2/L3-hot) to hide latency under c1
    f4v xc[4];
#pragma unroll
    for (int j = 0; j < 4; ++j)
        xc[j] = *(const f4v*)(xp + gbase + (size_t)j * 1024);

    // c1 = V1 u1 (5-tap)
    f4v c1f[4];
    {
        const uint2* b1 = u1b + fc * U1P + r0;
        h2v ua[8], ub[8];
#pragma unroll
        for (int i = 0; i < 8; ++i) {
            const uint2 w = b1[i];
            ua[i] = hb(w.x);
            ub[i] = hb(w.y);
        }
#pragma unroll
        for (int j = 0; j < 4; ++j) {
            const h2v s0 = W0 * (ua[j] + ua[j+4]) + W1 * (ua[j+1] + ua[j+3]) + W2 * ua[j+2];
            const h2v s1 = W0 * (ub[j] + ub[j+4]) + W1 * (ub[j+1] + ub[j+3]) + W2 * ub[j+2];
            c1f[j] = tof4(s0, s1);
        }
    }
#pragma unroll
    for (int j = 0; j < 4; ++j)
        __builtin_nontemporal_store(xc[j] - c1f[j],
            (f4v*)(op + 0 * HW + gbase + (size_t)j * 1024));

    // c2 = V2 u2 (13-tap dense), dual even/odd accumulators
    f4v c2f[4];
    {
        const uint2* b2 = u2b + fc * U2P + r0;
        h2v A[4][2] = {}, B[4][2] = {};
#pragma unroll
        for (int i = 0; i < 16; ++i) {
            const uint2 w = b2[i];
            const h2v v0 = hb(w.x), v1 = hb(w.y);
#pragma unroll
            for (int j = 0; j < 4; ++j) {
                const int m = i - j;
                if (m >= 0 && m <= 12) {
                    const h2v k = hsplat(K13f[m]);
                    if (i & 1) { B[j][0] += k * v0; B[j][1] += k * v1; }
                    else       { A[j][0] += k * v0; A[j][1] += k * v1; }
                }
            }
        }
#pragma unroll
        for (int j = 0; j < 4; ++j)
            c2f[j] = tof4(A[j][0] + B[j][0], A[j][1] + B[j][1]);
    }
#pragma unroll
    for (int j = 0; j < 4; ++j)
        __builtin_nontemporal_store(c1f[j] - c2f[j],
            (f4v*)(op + 1 * HW + gbase + (size_t)j * 1024));

    // c3 = V3 u3 (29-tap dense, u3 in xs cols 0..15), dual accumulators
    f4v c3f[4];
    {
        const uint2* b3 = xsw + fc * XCP + r0;
        h2v A[4][2] = {}, B[4][2] = {};
#pragma unroll
        for (int i = 0; i < 32; ++i) {
            const uint2 w = b3[i];
            const h2v v0 = hb(w.x), v1 = hb(w.y);
#pragma unroll
            for (int j = 0; j < 4; ++j) {
                const int m = i - j;
                if (m >= 0 && m <= 28) {
                    const h2v k = hsplat(K29f[m]);
                    if (i & 1) { B[j][0] += k * v0; B[j][1] += k * v1; }
                    else       { A[j][0] += k * v0; A[j][1] += k * v1; }
                }
            }
        }
#pragma unroll
        for (int j = 0; j < 4; ++j)
            c3f[j] = tof4(A[j][0] + B[j][0], A[j][1] + B[j][1]);
    }
#pragma unroll
    for (int j = 0; j < 4; ++j) {
        __builtin_nontemporal_store(c2f[j] - c3f[j],
            (f4v*)(op + 2 * HW + gbase + (size_t)j * 1024));
        __builtin_nontemporal_store(c3f[j],
            (f4v*)(op + 3 * HW + gbase + (size_t)j * 1024));
    }
}

extern "C" void kernel_launch(void* const* d_in, const int* in_sizes, int n_in,
                              void* d_out, int out_size, void* d_ws, size_t ws_size,
                              hipStream_t stream)
{
    const float* x = (const float*)d_in[0];
    float* out = (float*)d_out;
    uwt3_kernel<<<dim3(4096), dim3(TB), 0, stream>>>(x, out);
}